// Round 6
// baseline (556.303 us; speedup 1.0000x reference)
//
#include <hip/hip_runtime.h>
#include <hip/hip_cooperative_groups.h>
#include <math.h>

namespace cg = cooperative_groups;

#define S_LEN 2048
#define DMODEL 1024
#define NHEAD 16
#define DHEAD 64
#define WIN 128
#define NQKV 1152

typedef _Float16 f16x8 __attribute__((ext_vector_type(8)));
typedef float f32x4 __attribute__((ext_vector_type(4)));

__device__ __forceinline__ ushort f2h(float f) {
  union { _Float16 h; ushort u; } v; v.h = (_Float16)f; return v.u;
}

typedef __attribute__((address_space(1))) const unsigned GU;
typedef __attribute__((address_space(3))) unsigned LU;
__device__ __forceinline__ void async16(const ushort* g, ushort* l) {
  __builtin_amdgcn_global_load_lds((GU*)g, (LU*)l, 16, 0, 0);
}

// ---------------------------------------------------------------- gemm 64x64 tile (R5-verified body)
// R5 schedule: 2-deep dbuf, prefetch issued BEFORE compute, plain __syncthreads per
// K-tile. XOR chunk swizzle: LDS dest linear (global_load_lds req), global source
// chunk pre-swizzled by (lane&7)^(row&7); ds_read applies the same involution.
// Wave w (2x2) computes 32x32: rows wm=(w>>1)*32, cols wn=(w&1)*32. acc[2][2]. K=1024.
// lds layout (ushort offsets): sA[b] = lds + b*4096, sB[b] = lds + 8192 + b*4096 (32 KiB).
template<int MODE>
__device__ __forceinline__ void gemm_tile(
    ushort* lds, const ushort* __restrict__ A, const ushort* __restrict__ B,
    const float* __restrict__ bias, float* __restrict__ Cout,
    ushort* __restrict__ k16, ushort* __restrict__ vT, ushort* __restrict__ q16,
    int m0, int n0, int N) {
  const int K = DMODEL;
  const int t = threadIdx.x;
  const int w = t >> 6, lane = t & 63;
  const int quad = lane >> 4, l16 = lane & 15;
  const int wm = (w >> 1) * 32, wn = (w & 1) * 32;

  const int lr = lane >> 3;
  const int lc = (lane & 7) ^ lr;
  const size_t aBase = (size_t)(m0 + 16 * w + lr) * K + lc * 8;  // wave stages 16 A-rows
  const size_t bBase = (size_t)(n0 + 16 * w + lr) * K + lc * 8;  // wave stages 16 B-rows

  f32x4 acc[2][2] = {};

  auto STAGE = [&](int ktile, int b) {
    const size_t koff = (size_t)ktile << 6;
    ushort* sA = lds + b * 4096;
    ushort* sB = lds + 8192 + b * 4096;
#pragma unroll
    for (int i = 0; i < 2; ++i) {
      async16(A + aBase + (size_t)(8 * i) * K + koff, &sA[(16 * w + 8 * i) * 64]);
      async16(B + bBase + (size_t)(8 * i) * K + koff, &sB[(16 * w + 8 * i) * 64]);
    }
  };

  STAGE(0, 0);
  __syncthreads();

  const int NT = K >> 6;   // 16
  for (int kt = 0; kt < NT; ++kt) {
    const int cur = kt & 1;
    if (kt + 1 < NT) STAGE(kt + 1, cur ^ 1);

    const ushort* sA = lds + cur * 4096;
    const ushort* sB = lds + 8192 + cur * 4096;
    f16x8 af[2][2], bf[2][2];
#pragma unroll
    for (int kst = 0; kst < 2; ++kst) {
      const int cp = ((kst << 2) | quad) ^ (l16 & 7);   // row&7 == l16&7
#pragma unroll
      for (int i = 0; i < 2; ++i) {
        af[kst][i] = *(const f16x8*)(&sA[(wm + 16 * i + l16) * 64 + cp * 8]);
        bf[kst][i] = *(const f16x8*)(&sB[(wn + 16 * i + l16) * 64 + cp * 8]);
      }
    }
#pragma unroll
    for (int kst = 0; kst < 2; ++kst)
#pragma unroll
      for (int i = 0; i < 2; ++i)
#pragma unroll
        for (int j = 0; j < 2; ++j)
          acc[i][j] = __builtin_amdgcn_mfma_f32_16x16x32_f16(af[kst][i], bf[kst][j], acc[i][j], 0, 0, 0);
    __syncthreads();
  }

#pragma unroll
  for (int i = 0; i < 2; ++i)
#pragma unroll
    for (int j = 0; j < 2; ++j) {
      const int cb = n0 + wn + 16 * j;      // lane-uniform column base
      const int col = cb + l16;
      if (MODE == 0) {
        const float b = bias[col];
#pragma unroll
        for (int r = 0; r < 4; ++r) {
          const int row = m0 + wm + 16 * i + quad * 4 + r;
          Cout[(size_t)row * N + col] = acc[i][j][r] + b;
        }
      } else {
        const float bscale = (cb >= 2 * DHEAD) ? 8.0f : 1.0f;
        const float b = bias[col] * bscale;
#pragma unroll
        for (int r = 0; r < 4; ++r) {
          const int row = m0 + wm + 16 * i + quad * 4 + r;
          const ushort h = f2h(acc[i][j][r] + b);
          if (cb >= 2 * DHEAD) {
            q16[(size_t)row * DMODEL + (col - 2 * DHEAD)] = h;
          } else if (cb < DHEAD) {
            k16[(size_t)row * DHEAD + col] = h;
          } else {
            vT[(size_t)(col - DHEAD) * S_LEN + row] = h;
          }
        }
      }
    }
}

// ---------------------------------------------------------------- attn body (R5-verified, QT=4)
// One query per wave; key window [jbase, jbase+160), jbase=(i0-127)&~7 (clamped 0).
// lds: Ksw[160][64] (chunk-swizzled) aliased by P[64][176]; Vt = lds + 64*176.
#define QT 4
#define NTK 10
#define KST 5
#define PSTR 176

__device__ __forceinline__ void attn_body(
    ushort* lds, int blk, const ushort* __restrict__ k16,
    const ushort* __restrict__ vT, const ushort* __restrict__ q16,
    ushort* __restrict__ obuf) {
  ushort* Ksw = lds;                  // [160][64] = 20,480 B (inside P region)
  ushort* P   = lds;                  // [64][176] = 22,528 B
  ushort* Vt  = lds + 64 * PSTR;      // [64][176] = 22,528 B

  const int t = threadIdx.x;
  const int i0 = blk * QT;
  const int jbase = (i0 >= WIN - 1) ? ((i0 - (WIN - 1)) & ~7) : 0;
  const int w = t >> 6, lane = t & 63;
  const int quad = lane >> 4, l16 = lane & 15;
  const int qg = i0 + w;              // this wave's query

  // ---- stage K: 20 async 1KB instrs, XOR chunk swizzle
#pragma unroll
  for (int i = 0; i < 5; ++i) {
    const int n = 5 * w + i;                 // 0..19, 8 rows each
    const int r = 8 * n + (lane >> 3);
    const int cs = (lane & 7) ^ (r & 7);
    async16(k16 + (size_t)(jbase + r) * DHEAD + cs * 8, &Ksw[n * 512]);
  }
  // ---- stage Vt[64][160] from vT (16B aligned since jbase%8==0)
  {
    const int d = t >> 2, p = t & 3;
#pragma unroll
    for (int it = 0; it < 5; ++it) {
      const int c = p + 4 * it;              // 0..19
      const uint4 raw = *(const uint4*)(vT + (size_t)d * S_LEN + jbase + c * 8);
      *(uint4*)(&Vt[d * PSTR + c * 8]) = raw;
    }
  }
  // ---- Q fragments: lane m-row = head = l16
  f16x8 qf[2];
  {
    const size_t qbase = (size_t)qg * DMODEL + l16 * DHEAD;
#pragma unroll
    for (int kst = 0; kst < 2; ++kst)
      qf[kst] = *(const f16x8*)(q16 + qbase + kst * 32 + quad * 8);
  }
  __syncthreads();

  // ---- QK^T: acc[nt], rows=heads (quad*4+r), cols=keys (nt*16+l16)
  f32x4 acc[NTK] = {};
#pragma unroll
  for (int nt = 0; nt < NTK; ++nt) {
#pragma unroll
    for (int kst = 0; kst < 2; ++kst) {
      const int cp = ((kst << 2) | quad) ^ (l16 & 7);
      const f16x8 bf = *(const f16x8*)(&Ksw[(nt * 16 + l16) * 64 + cp * 8]);
      acc[nt] = __builtin_amdgcn_mfma_f32_16x16x32_f16(qf[kst], bf, acc[nt], 0, 0, 0);
    }
  }
  __syncthreads();  // K region dead; Vt stores drained

  // ---- mask + softmax (regs/shfl over 16 lanes), P -> LDS f16
  float inv_l[4];
#pragma unroll
  for (int nt = 0; nt < NTK; ++nt) {
    const int jg = jbase + nt * 16 + l16;
    const bool valid = (jg <= qg) && (jg > qg - WIN);
#pragma unroll
    for (int r = 0; r < 4; ++r)
      if (!valid) acc[nt][r] = -1e30f;
  }
#pragma unroll
  for (int r = 0; r < 4; ++r) {
    float m = acc[0][r];
#pragma unroll
    for (int nt = 1; nt < NTK; ++nt) m = fmaxf(m, acc[nt][r]);
#pragma unroll
    for (int off = 1; off < 16; off <<= 1) m = fmaxf(m, __shfl_xor(m, off));
    float s = 0.f;
#pragma unroll
    for (int nt = 0; nt < NTK; ++nt) {
      const float e = __expf(acc[nt][r] - m);
      acc[nt][r] = e;
      s += e;
    }
#pragma unroll
    for (int off = 1; off < 16; off <<= 1) s += __shfl_xor(s, off);
    inv_l[r] = 1.0f / s;
  }
  {
    const int mrow0 = w * 16 + quad * 4;
#pragma unroll
    for (int r = 0; r < 4; ++r)
#pragma unroll
      for (int nt = 0; nt < NTK; ++nt)
        P[(mrow0 + r) * PSTR + nt * 16 + l16] = f2h(acc[nt][r]);
  }
  __syncthreads();

  // ---- PV: o[nd], rows=heads, cols=d (nd*16+l16); 5 K-steps over 160 keys
  f32x4 o[4] = {};
#pragma unroll
  for (int kst = 0; kst < KST; ++kst) {
    const f16x8 a = *(const f16x8*)(&P[(w * 16 + l16) * PSTR + kst * 32 + quad * 8]);
#pragma unroll
    for (int nd = 0; nd < 4; ++nd) {
      const f16x8 b = *(const f16x8*)(&Vt[(nd * 16 + l16) * PSTR + kst * 32 + quad * 8]);
      o[nd] = __builtin_amdgcn_mfma_f32_16x16x32_f16(a, b, o[nd], 0, 0, 0);
    }
  }

  // ---- epilogue: normalize, write obuf f16
  {
    const size_t obase = (size_t)qg * DMODEL;
#pragma unroll
    for (int nd = 0; nd < 4; ++nd)
#pragma unroll
      for (int r = 0; r < 4; ++r) {
        const int col = (quad * 4 + r) * DHEAD + nd * 16 + l16;
        obuf[obase + col] = f2h(o[nd][r] * inv_l[r]);
      }
  }
}

// ---------------------------------------------------------------- fused cooperative mega-kernel
// 512 blocks x 256 threads, 2 blocks/CU co-resident (LDS 45,056 B <= 160K/2, 8 waves/CU).
// Removes 3 inter-dispatch boundaries (launch + drain + cold ramp each) and keeps
// intermediates L2/L3-warm. grid.sync() + __threadfence() (release before, acquire
// after) handles cross-XCD L2 non-coherence (G16) for global intermediates.
__global__ __launch_bounds__(256)
void mega_kernel(const float4* __restrict__ x, const float4* __restrict__ wq,
                 const float4* __restrict__ wo,
                 const float* __restrict__ bqkv, const float* __restrict__ bout,
                 ushort* __restrict__ x16, ushort* __restrict__ w16,
                 ushort* __restrict__ wo16, ushort* __restrict__ k16,
                 ushort* __restrict__ vT, ushort* __restrict__ q16,
                 ushort* __restrict__ obuf, float* __restrict__ out) {
  __shared__ __align__(16) ushort lds[22528];   // 45,056 B union (attn=45K, gemm=32K)
  cg::grid_group grid = cg::this_grid();

  // ---- phase 0: convert fp32 -> f16 (grid-stride)
  {
    const int NX4 = (S_LEN * DMODEL) / 4;       // 524288
    const int NW4 = (NQKV * DMODEL) / 4;        // 294912
    const int NO4 = (DMODEL * DMODEL) / 4;      // 262144
    const int total = NX4 + NW4 + NO4;          // 1081344
    ushort4* x16v  = (ushort4*)x16;
    ushort4* w16v  = (ushort4*)w16;
    ushort4* wo16v = (ushort4*)wo16;
    for (int i = blockIdx.x * 256 + threadIdx.x; i < total; i += gridDim.x * 256) {
      if (i < NX4) {
        const float4 v = x[i];
        ushort4 h; h.x = f2h(v.x); h.y = f2h(v.y); h.z = f2h(v.z); h.w = f2h(v.w);
        x16v[i] = h;
      } else if (i < NX4 + NW4) {
        const int j = i - NX4;
        const float s = ((j >> 8) >= 2 * DHEAD) ? 8.0f : 1.0f;  // fold sqrt(D) into q-rows
        const float4 v = wq[j];
        ushort4 h; h.x = f2h(v.x * s); h.y = f2h(v.y * s); h.z = f2h(v.z * s); h.w = f2h(v.w * s);
        w16v[j] = h;
      } else {
        const int j = i - NX4 - NW4;
        const float4 v = wo[j];
        ushort4 h; h.x = f2h(v.x); h.y = f2h(v.y); h.z = f2h(v.z); h.w = f2h(v.w);
        wo16v[j] = h;
      }
    }
  }
  __threadfence();
  grid.sync();
  __threadfence();

  // ---- phase 1: QKV GEMM — 576 tiles of 64x64 (32 m x 18 n), grid-strided
  for (int tile = blockIdx.x; tile < 32 * (NQKV / 64); tile += gridDim.x) {
    const int m0 = (tile & 31) * 64;
    const int n0 = (tile >> 5) * 64;
    gemm_tile<1>(lds, x16, w16, bqkv, nullptr, k16, vT, q16, m0, n0, NQKV);
  }
  __threadfence();
  grid.sync();
  __threadfence();

  // ---- phase 2: attention — 512 blocks, 1:1
  attn_body(lds, blockIdx.x, k16, vT, q16, obuf);
  __threadfence();
  grid.sync();
  __threadfence();

  // ---- phase 3: out GEMM — 512 tiles of 64x64 (32 m x 16 n), 1:1
  {
    const int tile = blockIdx.x;
    const int m0 = (tile & 31) * 64;
    const int n0 = (tile >> 5) * 64;
    gemm_tile<0>(lds, obuf, wo16, bout, out, nullptr, nullptr, nullptr, m0, n0, DMODEL);
  }
}

// ---------------------------------------------------------------- launch
extern "C" void kernel_launch(void* const* d_in, const int* in_sizes, int n_in,
                              void* d_out, int out_size, void* d_ws, size_t ws_size,
                              hipStream_t stream) {
  const float4* x    = (const float4*)d_in[0];
  const float4* Wqkv = (const float4*)d_in[1];
  const float*  bqkv = (const float*)d_in[2];
  const float4* Wout = (const float4*)d_in[3];
  const float*  bout = (const float*)d_in[4];
  float* out = (float*)d_out;

  char* w = (char*)d_ws;
  ushort* x16  = (ushort*)(w + 0);          // 4,194,304 B
  ushort* w16  = (ushort*)(w + 4194304);    // 2,359,296 B
  ushort* wo16 = (ushort*)(w + 6553600);    // 2,097,152 B
  ushort* k16  = (ushort*)(w + 8650752);    // 270,336 B  (2112 rows x 64; rows >=2048 stay 0xAA)
  ushort* vT   = (ushort*)(w + 8921088);    // 270,336 B  (64 x 2048 + 8KB slack, stays 0xAA)
  ushort* q16  = (ushort*)(w + 9191424);    // 4,194,304 B
  ushort* obuf = (ushort*)(w + 13385728);   // 4,194,304 B   (total ~17.6 MB)

  void* kargs[] = {
    (void*)&x, (void*)&Wqkv, (void*)&Wout, (void*)&bqkv, (void*)&bout,
    (void*)&x16, (void*)&w16, (void*)&wo16, (void*)&k16, (void*)&vT,
    (void*)&q16, (void*)&obuf, (void*)&out
  };
  hipLaunchCooperativeKernel((const void*)mega_kernel, dim3(512), dim3(256),
                             kargs, 0, stream);
}

// Round 7
// 105.372 us; speedup vs baseline: 5.2794x; 5.2794x over previous
//
#include <hip/hip_runtime.h>
#include <math.h>

#define S_LEN 2048
#define DMODEL 1024
#define NHEAD 16
#define DHEAD 64
#define WIN 128
#define NQKV 1152

typedef _Float16 f16x8 __attribute__((ext_vector_type(8)));
typedef float f32x4 __attribute__((ext_vector_type(4)));

__device__ __forceinline__ ushort f2h(float f) {
  union { _Float16 h; ushort u; } v; v.h = (_Float16)f; return v.u;
}

typedef __attribute__((address_space(1))) const unsigned GU;
typedef __attribute__((address_space(3))) unsigned LU;
__device__ __forceinline__ void async16(const ushort* g, ushort* l) {
  __builtin_amdgcn_global_load_lds((GU*)g, (LU*)l, 16, 0, 0);
}

// ---------------------------------------------------------------- convert fp32 -> f16
__global__ __launch_bounds__(256)
void convert_kernel(const float4* __restrict__ x, const float4* __restrict__ wq,
                    const float4* __restrict__ wo,
                    ushort4* __restrict__ x16, ushort4* __restrict__ w16,
                    ushort4* __restrict__ wo16) {
  const int NX4 = (S_LEN * DMODEL) / 4;       // 524288
  const int NW4 = (NQKV * DMODEL) / 4;        // 294912
  const int NO4 = (DMODEL * DMODEL) / 4;      // 262144
  const int i = blockIdx.x * 256 + threadIdx.x;
  if (i < NX4) {
    const float4 v = x[i];
    ushort4 h; h.x = f2h(v.x); h.y = f2h(v.y); h.z = f2h(v.z); h.w = f2h(v.w);
    x16[i] = h;
  } else if (i < NX4 + NW4) {
    const int j = i - NX4;
    const float s = ((j >> 8) >= 2 * DHEAD) ? 8.0f : 1.0f;  // fold sqrt(D) into q-rows
    const float4 v = wq[j];
    ushort4 h; h.x = f2h(v.x * s); h.y = f2h(v.y * s); h.z = f2h(v.z * s); h.w = f2h(v.w * s);
    w16[j] = h;
  } else {
    const int j = i - NX4 - NW4;
    if (j < NO4) {
      const float4 v = wo[j];
      ushort4 h; h.x = f2h(v.x); h.y = f2h(v.y); h.z = f2h(v.z); h.w = f2h(v.w);
      wo16[j] = h;
    }
  }
}

// ---------------------------------------------------------------- 32x64 f16 GEMM
// R5 schedule (2-deep dbuf, prefetch issued BEFORE compute, plain __syncthreads per
// K-tile — the only schedule that has won on this problem), tile shrunk 64x64 ->
// 32x64 for TLP: LDS 24 KiB (6 blocks/CU capacity), grids 1152/1024 -> 4.5/4.0
// blocks/CU resident (vs R5's 2.25/2.0). R6 post-mortem: grid.sync costs ~130us each
// on this platform (MfmaUtil 0.85% in the fused kernel) -> launch boundaries are the
// CHEAP option; co-resident blocks covering the ~900cy cold-HBM staging misses is
// the lever that has moved every round (R2->R3 -11.6us, R4->R5 -3.7us).
// XOR chunk swizzle: LDS dest linear (global_load_lds req), global source chunk
// pre-swizzled by (lane&7)^(row&7); ds_read applies the same involution.
// 4 waves; wave w computes rows m0..m0+32 x cols n0+16w..n0+16w+16. acc[2].
// C[M][N] = A[M][K] * B[N][K]^T + bias. MODE 0: fp32 out. MODE 1: qkv epilogue ->
// k16[S][64] f16, vT[64][S] f16 (transposed!), q16[S][1024] f16 (bias x8 on q cols).
template<int MODE>
__global__ __launch_bounds__(256)
void gemm32(const ushort* __restrict__ A, const ushort* __restrict__ B,
            const float* __restrict__ bias, float* __restrict__ Cout,
            ushort* __restrict__ k16, ushort* __restrict__ vT, ushort* __restrict__ q16,
            int M, int N, int K) {
  __shared__ __align__(16) ushort sA[2][32 * 64];    // 2 x 4 KiB
  __shared__ __align__(16) ushort sB[2][64 * 64];    // 2 x 8 KiB  (total 24 KiB)
  const int t = threadIdx.x;
  const int w = t >> 6, lane = t & 63;
  const int quad = lane >> 4, l16 = lane & 15;
  const int wn = w * 16;
  const int m0 = blockIdx.x * 32, n0 = blockIdx.y * 64;

  // staging: each async16 covers 8 rows x 64B; source chunk pre-swizzled by row&7.
  // staged rows ≡ lane>>3 (mod 8) in every group (8w, 16w+8i are multiples of 8).
  const int lr = lane >> 3;
  const int lc = (lane & 7) ^ lr;
  const size_t aBase = (size_t)(m0 + 8 * w + lr) * K + lc * 8;   // wave stages 8 A-rows
  const size_t bBase = (size_t)(n0 + 16 * w + lr) * K + lc * 8;  // wave stages 16 B-rows

  f32x4 acc[2] = {};

  // 3 async16 per wave per tile (1 A + 2 B)
  auto STAGE = [&](int ktile, int b) {
    const size_t koff = (size_t)ktile << 6;
    async16(A + aBase + koff, &sA[b][(8 * w) * 64]);
#pragma unroll
    for (int i = 0; i < 2; ++i)
      async16(B + bBase + (size_t)(8 * i) * K + koff, &sB[b][(16 * w + 8 * i) * 64]);
  };

  // prologue: stage K-tile 0 into buffer 0
  STAGE(0, 0);
  __syncthreads();

  const int NT = K >> 6;   // 16
  for (int kt = 0; kt < NT; ++kt) {
    const int cur = kt & 1;
    // issue next tile's loads FIRST — latency hides under this tile's compute
    if (kt + 1 < NT) STAGE(kt + 1, cur ^ 1);

    f16x8 af[2][2], bf[2];
#pragma unroll
    for (int kst = 0; kst < 2; ++kst) {
      const int cp = ((kst << 2) | quad) ^ (l16 & 7);   // row ≡ l16 (mod 8): 16i,wn ≡ 0 mod 8
#pragma unroll
      for (int i = 0; i < 2; ++i)
        af[kst][i] = *(const f16x8*)(&sA[cur][(16 * i + l16) * 64 + cp * 8]);
      bf[kst] = *(const f16x8*)(&sB[cur][(wn + l16) * 64 + cp * 8]);
    }
#pragma unroll
    for (int kst = 0; kst < 2; ++kst)
#pragma unroll
      for (int i = 0; i < 2; ++i)
        acc[i] = __builtin_amdgcn_mfma_f32_16x16x32_f16(af[kst][i], bf[kst], acc[i], 0, 0, 0);
    __syncthreads();   // drains prefetch (residual only) + protects buffer reuse
  }

  const int cb = n0 + wn;               // lane-uniform column base
  const int col = cb + l16;
#pragma unroll
  for (int i = 0; i < 2; ++i) {
    if (MODE == 0) {
      const float b = bias[col];
#pragma unroll
      for (int r = 0; r < 4; ++r) {
        const int row = m0 + 16 * i + quad * 4 + r;
        Cout[(size_t)row * N + col] = acc[i][r] + b;
      }
    } else {
      const float bscale = (cb >= 2 * DHEAD) ? 8.0f : 1.0f;
      const float b = bias[col] * bscale;
#pragma unroll
      for (int r = 0; r < 4; ++r) {
        const int row = m0 + 16 * i + quad * 4 + r;
        const ushort h = f2h(acc[i][r] + b);
        if (cb >= 2 * DHEAD) {
          q16[(size_t)row * DMODEL + (col - 2 * DHEAD)] = h;
        } else if (cb < DHEAD) {
          k16[(size_t)row * DHEAD + col] = h;
        } else {
          vT[(size_t)(col - DHEAD) * S_LEN + row] = h;
        }
      }
    }
  }
}

// ---------------------------------------------------------------- MFMA flash attention (f16)
// QT=4: one query per wave, grid 512 blocks, LDS 45 KiB -> 2-3 blocks/CU co-resident
// (latency overlap across blocks). Key window [jbase, jbase+160), jbase=(i0-127)&~7
// (clamped 0); max needed span 138 <= 160. Keys >= S_LEN read allocated slack and are
// masked (exp(-1e30)=0). LDS: Ksw[160][64] (chunk-swizzled, global_load_lds), aliased
// after QK^T by P[64][176]; Vt[64][176] staged from vT. All masking in softmax.
#define QT 4
#define NTK 10
#define KST 5
#define PSTR 176

__global__ __launch_bounds__(256)
void attn_kernel(const ushort* __restrict__ k16, const ushort* __restrict__ vT,
                 const ushort* __restrict__ q16, ushort* __restrict__ obuf) {
  __shared__ __align__(16) ushort lds[64 * PSTR + 64 * PSTR];  // 45,056 B
  ushort* Ksw = lds;                  // [160][64] = 20,480 B (inside P region)
  ushort* P   = lds;                  // [64][176] = 22,528 B
  ushort* Vt  = lds + 64 * PSTR;      // [64][176] = 22,528 B

  const int t = threadIdx.x;
  const int i0 = blockIdx.x * QT;
  const int jbase = (i0 >= WIN - 1) ? ((i0 - (WIN - 1)) & ~7) : 0;
  const int w = t >> 6, lane = t & 63;
  const int quad = lane >> 4, l16 = lane & 15;
  const int qg = i0 + w;              // this wave's query

  // ---- stage K: 20 async 1KB instrs, XOR chunk swizzle (chunk c of row r at slot c^(r&7))
#pragma unroll
  for (int i = 0; i < 5; ++i) {
    const int n = 5 * w + i;                 // 0..19, 8 rows each
    const int r = 8 * n + (lane >> 3);
    const int cs = (lane & 7) ^ (r & 7);
    async16(k16 + (size_t)(jbase + r) * DHEAD + cs * 8, &Ksw[n * 512]);
  }
  // ---- stage Vt[64][160] from vT (16B aligned since jbase%8==0)
  {
    const int d = t >> 2, p = t & 3;
#pragma unroll
    for (int it = 0; it < 5; ++it) {
      const int c = p + 4 * it;              // 0..19
      const uint4 raw = *(const uint4*)(vT + (size_t)d * S_LEN + jbase + c * 8);
      *(uint4*)(&Vt[d * PSTR + c * 8]) = raw;
    }
  }
  // ---- Q fragments: lane m-row = head = l16
  f16x8 qf[2];
  {
    const size_t qbase = (size_t)qg * DMODEL + l16 * DHEAD;
#pragma unroll
    for (int kst = 0; kst < 2; ++kst)
      qf[kst] = *(const f16x8*)(q16 + qbase + kst * 32 + quad * 8);
  }
  __syncthreads();

  // ---- QK^T: acc[nt], rows=heads (quad*4+r), cols=keys (nt*16+l16)
  f32x4 acc[NTK] = {};
#pragma unroll
  for (int nt = 0; nt < NTK; ++nt) {
#pragma unroll
    for (int kst = 0; kst < 2; ++kst) {
      const int cp = ((kst << 2) | quad) ^ (l16 & 7);
      const f16x8 bf = *(const f16x8*)(&Ksw[(nt * 16 + l16) * 64 + cp * 8]);
      acc[nt] = __builtin_amdgcn_mfma_f32_16x16x32_f16(qf[kst], bf, acc[nt], 0, 0, 0);
    }
  }
  __syncthreads();  // K region dead; Vt stores drained

  // ---- mask + softmax (regs/shfl over 16 lanes), P -> LDS f16
  float inv_l[4];
#pragma unroll
  for (int nt = 0; nt < NTK; ++nt) {
    const int jg = jbase + nt * 16 + l16;
    const bool valid = (jg <= qg) && (jg > qg - WIN);
#pragma unroll
    for (int r = 0; r < 4; ++r)
      if (!valid) acc[nt][r] = -1e30f;
  }
#pragma unroll
  for (int r = 0; r < 4; ++r) {
    float m = acc[0][r];
#pragma unroll
    for (int nt = 1; nt < NTK; ++nt) m = fmaxf(m, acc[nt][r]);
#pragma unroll
    for (int off = 1; off < 16; off <<= 1) m = fmaxf(m, __shfl_xor(m, off));
    float s = 0.f;
#pragma unroll
    for (int nt = 0; nt < NTK; ++nt) {
      const float e = __expf(acc[nt][r] - m);
      acc[nt][r] = e;
      s += e;
    }
#pragma unroll
    for (int off = 1; off < 16; off <<= 1) s += __shfl_xor(s, off);
    inv_l[r] = 1.0f / s;
  }
  {
    const int mrow0 = w * 16 + quad * 4;
#pragma unroll
    for (int r = 0; r < 4; ++r)
#pragma unroll
      for (int nt = 0; nt < NTK; ++nt)
        P[(mrow0 + r) * PSTR + nt * 16 + l16] = f2h(acc[nt][r]);
  }
  __syncthreads();

  // ---- PV: o[nd], rows=heads, cols=d (nd*16+l16); 5 K-steps over 160 keys
  f32x4 o[4] = {};
#pragma unroll
  for (int kst = 0; kst < KST; ++kst) {
    const f16x8 a = *(const f16x8*)(&P[(w * 16 + l16) * PSTR + kst * 32 + quad * 8]);
#pragma unroll
    for (int nd = 0; nd < 4; ++nd) {
      const f16x8 b = *(const f16x8*)(&Vt[(nd * 16 + l16) * PSTR + kst * 32 + quad * 8]);
      o[nd] = __builtin_amdgcn_mfma_f32_16x16x32_f16(a, b, o[nd], 0, 0, 0);
    }
  }

  // ---- epilogue: normalize, write obuf f16
  {
    const size_t obase = (size_t)qg * DMODEL;
#pragma unroll
    for (int nd = 0; nd < 4; ++nd)
#pragma unroll
      for (int r = 0; r < 4; ++r) {
        const int col = (quad * 4 + r) * DHEAD + nd * 16 + l16;
        obuf[obase + col] = f2h(o[nd][r] * inv_l[r]);
      }
  }
}

// ---------------------------------------------------------------- launch
extern "C" void kernel_launch(void* const* d_in, const int* in_sizes, int n_in,
                              void* d_out, int out_size, void* d_ws, size_t ws_size,
                              hipStream_t stream) {
  const float* x    = (const float*)d_in[0];
  const float* Wqkv = (const float*)d_in[1];
  const float* bqkv = (const float*)d_in[2];
  const float* Wout = (const float*)d_in[3];
  const float* bout = (const float*)d_in[4];
  float* out = (float*)d_out;

  char* w = (char*)d_ws;
  ushort* x16  = (ushort*)(w + 0);          // 4,194,304 B
  ushort* w16  = (ushort*)(w + 4194304);    // 2,359,296 B
  ushort* wo16 = (ushort*)(w + 6553600);    // 2,097,152 B
  ushort* k16  = (ushort*)(w + 8650752);    // 270,336 B  (2112 rows x 64; rows >=2048 stay 0xAA)
  ushort* vT   = (ushort*)(w + 8921088);    // 270,336 B  (64 x 2048 + 8KB slack, stays 0xAA)
  ushort* q16  = (ushort*)(w + 9191424);    // 4,194,304 B
  ushort* obuf = (ushort*)(w + 13385728);   // 4,194,304 B   (total ~17.6 MB)

  convert_kernel<<<4224, 256, 0, stream>>>(
      (const float4*)x, (const float4*)Wqkv, (const float4*)Wout,
      (ushort4*)x16, (ushort4*)w16, (ushort4*)wo16);

  dim3 g1(S_LEN / 32, NQKV / 64);  // 64 x 18 = 1152
  gemm32<1><<<g1, 256, 0, stream>>>(x16, w16, bqkv, nullptr, k16, vT, q16,
                                    S_LEN, NQKV, DMODEL);

  attn_kernel<<<S_LEN / QT, 256, 0, stream>>>(k16, vT, q16, obuf);  // 512 blocks

  dim3 g2(S_LEN / 32, DMODEL / 64);  // 64 x 16 = 1024
  gemm32<0><<<g2, 256, 0, stream>>>(obuf, wo16, bout, out, nullptr, nullptr, nullptr,
                                    S_LEN, DMODEL, DMODEL);
}